// Round 5
// baseline (483.014 us; speedup 1.0000x reference)
//
#include <hip/hip_runtime.h>
#include <hip/hip_bf16.h>

// Problem constants (from reference)
#define BATCH 512
#define NKER  256
#define LEN   1000      // embedding input length
#define EDIM  3
#define OUTN  128
#define NROWS (BATCH * NKER)      // 131072
#define NF4   (LEN / 4)           // 250 float4 per row
#define FC_IN (EDIM * NKER)       // 768
#define S2_ROWS 4                 // batch rows per stage-2 block

#define DOT4(a, w) ((a).x*(w).x + (a).y*(w).y + (a).z*(w).z + (a).w*(w).w)

// ---------------- Stage 1: y[b,k,e] = sum_l x[b,k,l] * W_emb[e,l] ----------
// One wave per PAIR of consecutive rows per iteration (8 strided pairs/wave).
// W_emb in LDS (read once per pair, used for both rows). Next pair's 8 loads
// are issued right after the current DOT4s consume the registers (register
// reuse: zero extra VGPR) so HBM loads stay in flight through the reduce.
// Reduce: {1,2,4} butterfly on 6 values (intra-row DPP), 6-way lane select,
// {8,16,32} on one value; lanes 0-5 store 24B contiguous.
// __launch_bounds__(256,8) pins VGPR <= 64 -> 8 waves/SIMD.
__global__ __launch_bounds__(256, 8) void stage1_emb(const float* __restrict__ x,
                                                     const float* __restrict__ W_emb,
                                                     float* __restrict__ y) {
    __shared__ float w_s[EDIM][LEN];   // 12 KB
    for (int i = threadIdx.x; i < EDIM * LEN; i += 256) {
        w_s[i / LEN][i % LEN] = W_emb[i];
    }
    __syncthreads();

    const int wave = threadIdx.x >> 6;
    const int lane = threadIdx.x & 63;
    const int gw = blockIdx.x * 4 + wave;           // global wave id, 0..8191

    const bool tail = (lane < NF4 - 192);           // lane < 58 has a 4th slice
    const int f3 = tail ? (lane + 192) : 0;         // clamped LDS index (x zeroed)
    const float4 z4 = make_float4(0.f, 0.f, 0.f, 0.f);

    const float4* w0p = reinterpret_cast<const float4*>(&w_s[0][0]);
    const float4* w1p = reinterpret_cast<const float4*>(&w_s[1][0]);
    const float4* w2p = reinterpret_cast<const float4*>(&w_s[2][0]);

    // Prime: load first pair
    float4 a0, a1, a2, a3, b0, b1, b2, b3;
    {
        const float4* xa = reinterpret_cast<const float4*>(x + (size_t)(gw * 2) * LEN);
        const float4* xb = reinterpret_cast<const float4*>(x + (size_t)(gw * 2 + 1) * LEN);
        a0 = xa[lane]; a1 = xa[lane + 64]; a2 = xa[lane + 128]; a3 = tail ? xa[lane + 192] : z4;
        b0 = xb[lane]; b1 = xb[lane + 64]; b2 = xb[lane + 128]; b3 = tail ? xb[lane + 192] : z4;
    }

    #pragma unroll 1
    for (int i = 0; i < 8; ++i) {
        const int rowA = gw * 2 + i * 16384;        // pairs strided across array

        float sA0, sA1, sA2, sB0, sB1, sB2;
        {
            float4 w;
            w = w0p[lane];       sA0  = DOT4(a0, w);  sB0  = DOT4(b0, w);
            w = w1p[lane];       sA1  = DOT4(a0, w);  sB1  = DOT4(b0, w);
            w = w2p[lane];       sA2  = DOT4(a0, w);  sB2  = DOT4(b0, w);
            w = w0p[lane + 64];  sA0 += DOT4(a1, w);  sB0 += DOT4(b1, w);
            w = w1p[lane + 64];  sA1 += DOT4(a1, w);  sB1 += DOT4(b1, w);
            w = w2p[lane + 64];  sA2 += DOT4(a1, w);  sB2 += DOT4(b1, w);
            w = w0p[lane + 128]; sA0 += DOT4(a2, w);  sB0 += DOT4(b2, w);
            w = w1p[lane + 128]; sA1 += DOT4(a2, w);  sB1 += DOT4(b2, w);
            w = w2p[lane + 128]; sA2 += DOT4(a2, w);  sB2 += DOT4(b2, w);
            w = w0p[f3];         sA0 += DOT4(a3, w);  sB0 += DOT4(b3, w);
            w = w1p[f3];         sA1 += DOT4(a3, w);  sB1 += DOT4(b3, w);
            w = w2p[f3];         sA2 += DOT4(a3, w);  sB2 += DOT4(b3, w);
        }

        // Issue next pair's loads NOW, reusing the just-consumed registers.
        if (i + 1 < 8) {    // uniform (scalar) branch
            const int rowN = gw * 2 + (i + 1) * 16384;
            const float4* xa = reinterpret_cast<const float4*>(x + (size_t)rowN * LEN);
            const float4* xb = reinterpret_cast<const float4*>(x + (size_t)(rowN + 1) * LEN);
            a0 = xa[lane]; a1 = xa[lane + 64]; a2 = xa[lane + 128]; a3 = tail ? xa[lane + 192] : z4;
            b0 = xb[lane]; b1 = xb[lane + 64]; b2 = xb[lane + 128]; b3 = tail ? xb[lane + 192] : z4;
        }
        __builtin_amdgcn_sched_barrier(0);   // keep load issue here (don't sink below reduce)

        // Reduce part 1: sum within each 8-lane group (masks 1,2,4 — DPP-cheap)
        #pragma unroll
        for (int m = 1; m <= 4; m <<= 1) {
            sA0 += __shfl_xor(sA0, m);
            sA1 += __shfl_xor(sA1, m);
            sA2 += __shfl_xor(sA2, m);
            sB0 += __shfl_xor(sB0, m);
            sB1 += __shfl_xor(sB1, m);
            sB2 += __shfl_xor(sB2, m);
        }
        // Lane l now holds the 8-lane-group partial (group g = l>>3) of all 6
        // values. Lane l finishes value v = l&7 (v=0..5 meaningful).
        const int v = lane & 7;
        float val = sA0;
        val = (v == 1) ? sA1 : val;
        val = (v == 2) ? sA2 : val;
        val = (v == 3) ? sB0 : val;
        val = (v == 4) ? sB1 : val;
        val = (v == 5) ? sB2 : val;
        // Reduce part 2: sum the 8 group-partials (masks 8,16,32) for own value
        val += __shfl_xor(val, 8);
        val += __shfl_xor(val, 16);
        val += __shfl_xor(val, 32);

        // Lanes 0..5 hold y[rowA][0..2], y[rowA+1][0..2] -> contiguous 24B store
        if (lane < 6) {
            y[(size_t)rowA * EDIM + lane] = val;
        }
    }
}

// ---------------- Stage 1.5: transpose W_fc2 [OUT, 768] -> Wt [768, OUT] ----
__global__ __launch_bounds__(256) void transpose_wfc2(const float* __restrict__ W,
                                                      float* __restrict__ Wt) {
    int idx = blockIdx.x * 256 + threadIdx.x;   // index into Wt (coalesced write)
    if (idx < FC_IN * OUTN) {
        int j = idx >> 7;          // 0..767
        int o = idx & (OUTN - 1);  // 0..127
        Wt[idx] = W[o * FC_IN + j];
    }
}

// ---------------- Stage 2: out[b,o] = sum_j y[b,j] * Wt[j,o] + bias[o] ------
// 4 batch rows per block, 256 threads (128 o x 2 j-halves), 128 blocks:
// Wt L2 traffic 201 MB -> 50 MB while keeping half-grid CU coverage + 4-acc ILP.
__global__ __launch_bounds__(256) void stage2_fc(const float* __restrict__ y,
                                                 const float* __restrict__ Wt,
                                                 const float* __restrict__ bias,
                                                 float* __restrict__ out) {
    __shared__ float ys[S2_ROWS * FC_IN];   // 12 KB
    __shared__ float part[S2_ROWS][OUTN];   // 2 KB
    const int b0 = blockIdx.x * S2_ROWS;

    const float4* ysrc = reinterpret_cast<const float4*>(y + (size_t)b0 * FC_IN);
    float4* ydst = reinterpret_cast<float4*>(&ys[0]);
    for (int i = threadIdx.x; i < S2_ROWS * FC_IN / 4; i += 256) ydst[i] = ysrc[i];
    __syncthreads();

    const int o = threadIdx.x & (OUTN - 1);
    const int h = threadIdx.x >> 7;               // 0 or 1
    const int j0 = h * (FC_IN / 2);

    float acc[S2_ROWS] = {0.f, 0.f, 0.f, 0.f};
    #pragma unroll 4
    for (int j = j0; j < j0 + FC_IN / 2; ++j) {
        const float w = Wt[j * OUTN + o];         // coalesced; L2-resident
        #pragma unroll
        for (int r = 0; r < S2_ROWS; ++r) acc[r] += ys[r * FC_IN + j] * w;  // LDS broadcast
    }

    if (h) {
        #pragma unroll
        for (int r = 0; r < S2_ROWS; ++r) part[r][o] = acc[r];
    }
    __syncthreads();
    if (!h) {
        const float bo = bias[o];
        #pragma unroll
        for (int r = 0; r < S2_ROWS; ++r) {
            out[(size_t)(b0 + r) * OUTN + o] = acc[r] + part[r][o] + bo;
        }
    }
}

extern "C" void kernel_launch(void* const* d_in, const int* in_sizes, int n_in,
                              void* d_out, int out_size, void* d_ws, size_t ws_size,
                              hipStream_t stream) {
    const float* x     = (const float*)d_in[0];   // [512, 256, 1000]
    const float* W_emb = (const float*)d_in[1];   // [3, 1000]
    const float* W_fc2 = (const float*)d_in[2];   // [128, 768]
    const float* b_fc2 = (const float*)d_in[3];   // [128]
    float* out = (float*)d_out;                   // [512, 128]

    // Workspace layout: y [131072*3] floats, then Wt [768*128] floats
    float* y  = (float*)d_ws;
    float* Wt = y + (size_t)NROWS * EDIM;

    // Transpose fc2 weight first (independent of stage 1)
    transpose_wfc2<<<(FC_IN * OUTN + 255) / 256, 256, 0, stream>>>(W_fc2, Wt);

    // Stage 1: 2048 blocks x 256 threads; each wave does 8 strided row-pairs
    stage1_emb<<<2048, 256, 0, stream>>>(x, W_emb, y);

    // Stage 2: 128 blocks, 4 batch rows each, 256 threads
    stage2_fc<<<BATCH / S2_ROWS, 256, 0, stream>>>(y, Wt, b_fc2, out);
}

// Round 6
// 145.812 us; speedup vs baseline: 3.3126x; 3.3126x over previous
//
#include <hip/hip_runtime.h>
#include <hip/hip_bf16.h>

// Problem constants (from reference)
#define BATCH 512
#define NKER  256
#define LEN   1000      // embedding input length
#define EDIM  3
#define OUTN  128
#define NROWS (BATCH * NKER)      // 131072
#define NF4   (LEN / 4)           // 250 float4 per row
#define FC_IN (EDIM * NKER)       // 768
#define S2_ROWS 4                 // batch rows per stage-2 block

#define DOT4(a, w) ((a).x*(w).x + (a).y*(w).y + (a).z*(w).z + (a).w*(w).w)

// ---------------- Stage 1: y[b,k,e] = sum_l x[b,k,l] * W_emb[e,l] ----------
// One wave per PAIR of consecutive rows per iteration (8 strided pairs/wave).
// W_emb in LDS (each W float4 read once per pair, used for both rows). All 8
// x loads issued at the top of each iteration; NO register carry across
// iterations and NO launch-bounds cap (round-4 lesson: forcing min-waves
// spilled the load buffer to scratch -> 4x regression).
// Reduce: {1,2,4} butterfly on 6 values, 6-way lane select, {8,16,32} on one
// value; lanes 0-5 store 24B contiguous.
__global__ __launch_bounds__(256) void stage1_emb(const float* __restrict__ x,
                                                  const float* __restrict__ W_emb,
                                                  float* __restrict__ y) {
    __shared__ float w_s[EDIM][LEN];   // 12 KB
    for (int i = threadIdx.x; i < EDIM * LEN; i += 256) {
        w_s[i / LEN][i % LEN] = W_emb[i];
    }
    __syncthreads();

    const int wave = threadIdx.x >> 6;
    const int lane = threadIdx.x & 63;
    const int gw = blockIdx.x * 4 + wave;           // global wave id, 0..8191

    const bool tail = (lane < NF4 - 192);           // lane < 58 has a 4th slice
    const int f3 = tail ? (lane + 192) : 0;         // clamped LDS index (x zeroed)
    const float4 z4 = make_float4(0.f, 0.f, 0.f, 0.f);

    const float4* w0p = reinterpret_cast<const float4*>(&w_s[0][0]);
    const float4* w1p = reinterpret_cast<const float4*>(&w_s[1][0]);
    const float4* w2p = reinterpret_cast<const float4*>(&w_s[2][0]);

    #pragma unroll 1
    for (int i = 0; i < 8; ++i) {
        const int rowA = gw * 2 + i * 16384;        // pairs strided across array
        const float4* xa = reinterpret_cast<const float4*>(x + (size_t)rowA * LEN);
        const float4* xb = reinterpret_cast<const float4*>(x + (size_t)(rowA + 1) * LEN);

        // Issue all 8 loads before any use (8 KB contiguous in flight per wave)
        float4 a0 = xa[lane];
        float4 a1 = xa[lane + 64];
        float4 a2 = xa[lane + 128];
        float4 a3 = tail ? xa[lane + 192] : z4;
        float4 b0 = xb[lane];
        float4 b1 = xb[lane + 64];
        float4 b2 = xb[lane + 128];
        float4 b3 = tail ? xb[lane + 192] : z4;

        float sA0, sA1, sA2, sB0, sB1, sB2;
        {
            float4 w;
            // chunk 0 (W read once, used for both rows)
            w = w0p[lane];       sA0  = DOT4(a0, w);  sB0  = DOT4(b0, w);
            w = w1p[lane];       sA1  = DOT4(a0, w);  sB1  = DOT4(b0, w);
            w = w2p[lane];       sA2  = DOT4(a0, w);  sB2  = DOT4(b0, w);
            // chunk 1
            w = w0p[lane + 64];  sA0 += DOT4(a1, w);  sB0 += DOT4(b1, w);
            w = w1p[lane + 64];  sA1 += DOT4(a1, w);  sB1 += DOT4(b1, w);
            w = w2p[lane + 64];  sA2 += DOT4(a1, w);  sB2 += DOT4(b1, w);
            // chunk 2
            w = w0p[lane + 128]; sA0 += DOT4(a2, w);  sB0 += DOT4(b2, w);
            w = w1p[lane + 128]; sA1 += DOT4(a2, w);  sB1 += DOT4(b2, w);
            w = w2p[lane + 128]; sA2 += DOT4(a2, w);  sB2 += DOT4(b2, w);
            // chunk 3 (tail; x zeroed for lanes >= 58, W index clamped)
            w = w0p[f3];         sA0 += DOT4(a3, w);  sB0 += DOT4(b3, w);
            w = w1p[f3];         sA1 += DOT4(a3, w);  sB1 += DOT4(b3, w);
            w = w2p[f3];         sA2 += DOT4(a3, w);  sB2 += DOT4(b3, w);
        }

        // Reduce part 1: sum within each 8-lane group (masks 1,2,4)
        #pragma unroll
        for (int m = 1; m <= 4; m <<= 1) {
            sA0 += __shfl_xor(sA0, m);
            sA1 += __shfl_xor(sA1, m);
            sA2 += __shfl_xor(sA2, m);
            sB0 += __shfl_xor(sB0, m);
            sB1 += __shfl_xor(sB1, m);
            sB2 += __shfl_xor(sB2, m);
        }
        // Lane l holds the 8-lane-group partial of all 6 values; lane l
        // finishes value v = l&7 (v=0..5 meaningful).
        const int v = lane & 7;
        float val = sA0;
        val = (v == 1) ? sA1 : val;
        val = (v == 2) ? sA2 : val;
        val = (v == 3) ? sB0 : val;
        val = (v == 4) ? sB1 : val;
        val = (v == 5) ? sB2 : val;
        // Reduce part 2: sum the 8 group-partials (masks 8,16,32)
        val += __shfl_xor(val, 8);
        val += __shfl_xor(val, 16);
        val += __shfl_xor(val, 32);

        // Lanes 0..5 hold y[rowA][0..2], y[rowA+1][0..2] -> contiguous 24B store
        if (lane < 6) {
            y[(size_t)rowA * EDIM + lane] = val;
        }
    }
}

// ---------------- Stage 1.5: transpose W_fc2 [OUT, 768] -> Wt [768, OUT] ----
__global__ __launch_bounds__(256) void transpose_wfc2(const float* __restrict__ W,
                                                      float* __restrict__ Wt) {
    int idx = blockIdx.x * 256 + threadIdx.x;   // index into Wt (coalesced write)
    if (idx < FC_IN * OUTN) {
        int j = idx >> 7;          // 0..767
        int o = idx & (OUTN - 1);  // 0..127
        Wt[idx] = W[o * FC_IN + j];
    }
}

// ---------------- Stage 2: out[b,o] = sum_j y[b,j] * Wt[j,o] + bias[o] ------
// 4 batch rows per block, 256 threads (128 o x 2 j-halves), 128 blocks.
__global__ __launch_bounds__(256) void stage2_fc(const float* __restrict__ y,
                                                 const float* __restrict__ Wt,
                                                 const float* __restrict__ bias,
                                                 float* __restrict__ out) {
    __shared__ float ys[S2_ROWS * FC_IN];   // 12 KB
    __shared__ float part[S2_ROWS][OUTN];   // 2 KB
    const int b0 = blockIdx.x * S2_ROWS;

    const float4* ysrc = reinterpret_cast<const float4*>(y + (size_t)b0 * FC_IN);
    float4* ydst = reinterpret_cast<float4*>(&ys[0]);
    for (int i = threadIdx.x; i < S2_ROWS * FC_IN / 4; i += 256) ydst[i] = ysrc[i];
    __syncthreads();

    const int o = threadIdx.x & (OUTN - 1);
    const int h = threadIdx.x >> 7;               // 0 or 1
    const int j0 = h * (FC_IN / 2);

    float acc[S2_ROWS] = {0.f, 0.f, 0.f, 0.f};
    #pragma unroll 4
    for (int j = j0; j < j0 + FC_IN / 2; ++j) {
        const float w = Wt[j * OUTN + o];         // coalesced; L2-resident
        #pragma unroll
        for (int r = 0; r < S2_ROWS; ++r) acc[r] += ys[r * FC_IN + j] * w;  // LDS broadcast
    }

    if (h) {
        #pragma unroll
        for (int r = 0; r < S2_ROWS; ++r) part[r][o] = acc[r];
    }
    __syncthreads();
    if (!h) {
        const float bo = bias[o];
        #pragma unroll
        for (int r = 0; r < S2_ROWS; ++r) {
            out[(size_t)(b0 + r) * OUTN + o] = acc[r] + part[r][o] + bo;
        }
    }
}

extern "C" void kernel_launch(void* const* d_in, const int* in_sizes, int n_in,
                              void* d_out, int out_size, void* d_ws, size_t ws_size,
                              hipStream_t stream) {
    const float* x     = (const float*)d_in[0];   // [512, 256, 1000]
    const float* W_emb = (const float*)d_in[1];   // [3, 1000]
    const float* W_fc2 = (const float*)d_in[2];   // [128, 768]
    const float* b_fc2 = (const float*)d_in[3];   // [128]
    float* out = (float*)d_out;                   // [512, 128]

    // Workspace layout: y [131072*3] floats, then Wt [768*128] floats
    float* y  = (float*)d_ws;
    float* Wt = y + (size_t)NROWS * EDIM;

    // Transpose fc2 weight first (independent of stage 1)
    transpose_wfc2<<<(FC_IN * OUTN + 255) / 256, 256, 0, stream>>>(W_fc2, Wt);

    // Stage 1: 2048 blocks x 256 threads; each wave does 8 strided row-pairs
    stage1_emb<<<2048, 256, 0, stream>>>(x, W_emb, y);

    // Stage 2: 128 blocks, 4 batch rows each, 256 threads
    stage2_fc<<<BATCH / S2_ROWS, 256, 0, stream>>>(y, Wt, b_fc2, out);
}

// Round 7
// 129.232 us; speedup vs baseline: 3.7376x; 1.1283x over previous
//
#include <hip/hip_runtime.h>
#include <hip/hip_bf16.h>

// Problem constants (from reference)
#define BATCH 512
#define NKER  256
#define LEN   1000      // embedding input length
#define EDIM  3
#define OUTN  128
#define NROWS (BATCH * NKER)      // 131072
#define NF4   (LEN / 4)           // 250 float4 per row
#define FC_IN (EDIM * NKER)       // 768

#define DOT4(a, w) ((a).x*(w).x + (a).y*(w).y + (a).z*(w).z + (a).w*(w).w)

// ---------------- Stage 1: y[b,k,e] = sum_l x[b,k,l] * W_emb[e,l] ----------
// One wave per PAIR of consecutive rows per iteration (8 strided pairs/wave).
// W_emb in LDS (each W float4 read once per pair, used for both rows). All 8
// x loads issued at the top of each iteration; no register carry, no
// launch-bounds min-waves cap (round-4 spill lesson).
// Reduce: {1,2,4} butterfly on 6 values, 6-way lane select, {8,16,32} on one
// value; lanes 0-5 store 24B contiguous.
__global__ __launch_bounds__(256) void stage1_emb(const float* __restrict__ x,
                                                  const float* __restrict__ W_emb,
                                                  float* __restrict__ y) {
    __shared__ float w_s[EDIM][LEN];   // 12 KB
    for (int i = threadIdx.x; i < EDIM * LEN; i += 256) {
        w_s[i / LEN][i % LEN] = W_emb[i];
    }
    __syncthreads();

    const int wave = threadIdx.x >> 6;
    const int lane = threadIdx.x & 63;
    const int gw = blockIdx.x * 4 + wave;           // global wave id, 0..8191

    const bool tail = (lane < NF4 - 192);           // lane < 58 has a 4th slice
    const int f3 = tail ? (lane + 192) : 0;         // clamped LDS index (x zeroed)
    const float4 z4 = make_float4(0.f, 0.f, 0.f, 0.f);

    const float4* w0p = reinterpret_cast<const float4*>(&w_s[0][0]);
    const float4* w1p = reinterpret_cast<const float4*>(&w_s[1][0]);
    const float4* w2p = reinterpret_cast<const float4*>(&w_s[2][0]);

    #pragma unroll 1
    for (int i = 0; i < 8; ++i) {
        const int rowA = gw * 2 + i * 16384;        // pairs strided across array
        const float4* xa = reinterpret_cast<const float4*>(x + (size_t)rowA * LEN);
        const float4* xb = reinterpret_cast<const float4*>(x + (size_t)(rowA + 1) * LEN);

        // Issue all 8 loads before any use (8 KB contiguous in flight per wave)
        float4 a0 = xa[lane];
        float4 a1 = xa[lane + 64];
        float4 a2 = xa[lane + 128];
        float4 a3 = tail ? xa[lane + 192] : z4;
        float4 b0 = xb[lane];
        float4 b1 = xb[lane + 64];
        float4 b2 = xb[lane + 128];
        float4 b3 = tail ? xb[lane + 192] : z4;

        float sA0, sA1, sA2, sB0, sB1, sB2;
        {
            float4 w;
            // chunk 0 (W read once, used for both rows)
            w = w0p[lane];       sA0  = DOT4(a0, w);  sB0  = DOT4(b0, w);
            w = w1p[lane];       sA1  = DOT4(a0, w);  sB1  = DOT4(b0, w);
            w = w2p[lane];       sA2  = DOT4(a0, w);  sB2  = DOT4(b0, w);
            // chunk 1
            w = w0p[lane + 64];  sA0 += DOT4(a1, w);  sB0 += DOT4(b1, w);
            w = w1p[lane + 64];  sA1 += DOT4(a1, w);  sB1 += DOT4(b1, w);
            w = w2p[lane + 64];  sA2 += DOT4(a1, w);  sB2 += DOT4(b1, w);
            // chunk 2
            w = w0p[lane + 128]; sA0 += DOT4(a2, w);  sB0 += DOT4(b2, w);
            w = w1p[lane + 128]; sA1 += DOT4(a2, w);  sB1 += DOT4(b2, w);
            w = w2p[lane + 128]; sA2 += DOT4(a2, w);  sB2 += DOT4(b2, w);
            // chunk 3 (tail; x zeroed for lanes >= 58, W index clamped)
            w = w0p[f3];         sA0 += DOT4(a3, w);  sB0 += DOT4(b3, w);
            w = w1p[f3];         sA1 += DOT4(a3, w);  sB1 += DOT4(b3, w);
            w = w2p[f3];         sA2 += DOT4(a3, w);  sB2 += DOT4(b3, w);
        }

        // Reduce part 1: sum within each 8-lane group (masks 1,2,4)
        #pragma unroll
        for (int m = 1; m <= 4; m <<= 1) {
            sA0 += __shfl_xor(sA0, m);
            sA1 += __shfl_xor(sA1, m);
            sA2 += __shfl_xor(sA2, m);
            sB0 += __shfl_xor(sB0, m);
            sB1 += __shfl_xor(sB1, m);
            sB2 += __shfl_xor(sB2, m);
        }
        // Lane l holds the 8-lane-group partial of all 6 values; lane l
        // finishes value v = l&7 (v=0..5 meaningful).
        const int v = lane & 7;
        float val = sA0;
        val = (v == 1) ? sA1 : val;
        val = (v == 2) ? sA2 : val;
        val = (v == 3) ? sB0 : val;
        val = (v == 4) ? sB1 : val;
        val = (v == 5) ? sB2 : val;
        // Reduce part 2: sum the 8 group-partials (masks 8,16,32)
        val += __shfl_xor(val, 8);
        val += __shfl_xor(val, 16);
        val += __shfl_xor(val, 32);

        // Lanes 0..5 hold y[rowA][0..2], y[rowA+1][0..2] -> contiguous 24B store
        if (lane < 6) {
            y[(size_t)rowA * EDIM + lane] = val;
        }
    }
}

// ---------------- Stage 1.5: transpose W_fc2 [OUT, 768] -> Wt [768, OUT] ----
__global__ __launch_bounds__(256) void transpose_wfc2(const float* __restrict__ W,
                                                      float* __restrict__ Wt) {
    int idx = blockIdx.x * 256 + threadIdx.x;   // index into Wt (coalesced write)
    if (idx < FC_IN * OUTN) {
        int j = idx >> 7;          // 0..767
        int o = idx & (OUTN - 1);  // 0..127
        Wt[idx] = W[o * FC_IN + j];
    }
}

// ---------------- Stage 2: out[b,o] = sum_j y[b,j] * Wt[j,o] + bias[o] ------
// Round-3 proven version: 512 blocks x 256 threads (128 o x 2 j-halves).
// Stage 2 is L2-latency-bound, not Wt-traffic-bound: max blocks = max TLP.
__global__ __launch_bounds__(256) void stage2_fc(const float* __restrict__ y,
                                                 const float* __restrict__ Wt,
                                                 const float* __restrict__ bias,
                                                 float* __restrict__ out) {
    __shared__ float ys[FC_IN];
    __shared__ float part[OUTN];
    const int b = blockIdx.x;
    for (int i = threadIdx.x; i < FC_IN; i += 256) ys[i] = y[(size_t)b * FC_IN + i];
    __syncthreads();

    const int o = threadIdx.x & (OUTN - 1);
    const int h = threadIdx.x >> 7;               // 0 or 1
    const int j0 = h * (FC_IN / 2);
    float acc = 0.f;
    #pragma unroll 8
    for (int j = j0; j < j0 + FC_IN / 2; ++j) {
        acc += ys[j] * Wt[j * OUTN + o];   // ys[j] broadcast; Wt coalesced across lanes
    }
    if (h) part[o] = acc;
    __syncthreads();
    if (!h) out[(size_t)b * OUTN + o] = acc + part[o] + bias[o];
}

extern "C" void kernel_launch(void* const* d_in, const int* in_sizes, int n_in,
                              void* d_out, int out_size, void* d_ws, size_t ws_size,
                              hipStream_t stream) {
    const float* x     = (const float*)d_in[0];   // [512, 256, 1000]
    const float* W_emb = (const float*)d_in[1];   // [3, 1000]
    const float* W_fc2 = (const float*)d_in[2];   // [128, 768]
    const float* b_fc2 = (const float*)d_in[3];   // [128]
    float* out = (float*)d_out;                   // [512, 128]

    // Workspace layout: y [131072*3] floats, then Wt [768*128] floats
    float* y  = (float*)d_ws;
    float* Wt = y + (size_t)NROWS * EDIM;

    // Transpose fc2 weight first (independent of stage 1)
    transpose_wfc2<<<(FC_IN * OUTN + 255) / 256, 256, 0, stream>>>(W_fc2, Wt);

    // Stage 1: 2048 blocks x 256 threads; each wave does 8 strided row-pairs
    stage1_emb<<<2048, 256, 0, stream>>>(x, W_emb, y);

    // Stage 2: one block per batch row, 256 threads (o x j-half)
    stage2_fc<<<BATCH, 256, 0, stream>>>(y, Wt, b_fc2, out);
}

// Round 8
// 111.154 us; speedup vs baseline: 4.3455x; 1.1626x over previous
//
#include <hip/hip_runtime.h>
#include <hip/hip_bf16.h>

// Problem constants (from reference)
#define BATCH 512
#define NKER  256
#define LEN   1000      // embedding input length
#define EDIM  3
#define OUTN  128
#define NROWS (BATCH * NKER)      // 131072
#define NF4   (LEN / 4)           // 250 float4 per row
#define FC_IN (EDIM * NKER)       // 768

typedef float fv4 __attribute__((ext_vector_type(4)));

#define DOT4(a, w) ((a)[0]*(w)[0] + (a)[1]*(w)[1] + (a)[2]*(w)[2] + (a)[3]*(w)[3])

// ---------------- Stage 1: y[b,k,e] = sum_l x[b,k,l] * W_emb[e,l] ----------
// Round-3 proven structure: one wave per PAIR of consecutive rows (8 strided
// pairs/wave). W_emb in LDS (each W float4 read once per pair, used for both
// rows). All 8 x loads issued at the top of each iteration; no register
// carry, no launch-bounds min-waves cap (round-4 spill lesson). Full 6-value
// butterfly reduce (6 independent chains = ILP; round-6 lane-select variant
// was ~11us slower). x loads are nontemporal (streamed once, no reuse).
__global__ __launch_bounds__(256) void stage1_emb(const float* __restrict__ x,
                                                  const float* __restrict__ W_emb,
                                                  float* __restrict__ y) {
    __shared__ float w_s[EDIM][LEN];   // 12 KB
    for (int i = threadIdx.x; i < EDIM * LEN; i += 256) {
        w_s[i / LEN][i % LEN] = W_emb[i];
    }
    __syncthreads();

    const int wave = threadIdx.x >> 6;
    const int lane = threadIdx.x & 63;
    const int gw = blockIdx.x * 4 + wave;           // global wave id, 0..8191

    const bool tail = (lane < NF4 - 192);           // lane < 58 has a 4th slice
    const int f3 = tail ? (lane + 192) : 0;         // clamped LDS index (x zeroed)
    const fv4 z4 = {0.f, 0.f, 0.f, 0.f};

    const fv4* w0p = reinterpret_cast<const fv4*>(&w_s[0][0]);
    const fv4* w1p = reinterpret_cast<const fv4*>(&w_s[1][0]);
    const fv4* w2p = reinterpret_cast<const fv4*>(&w_s[2][0]);

    #pragma unroll 1
    for (int i = 0; i < 8; ++i) {
        const int rowA = gw * 2 + i * 16384;        // pairs strided across array
        const fv4* xa = reinterpret_cast<const fv4*>(x + (size_t)rowA * LEN);
        const fv4* xb = reinterpret_cast<const fv4*>(x + (size_t)(rowA + 1) * LEN);

        // Issue all 8 loads before any use (8 KB contiguous in flight per wave)
        fv4 a0 = __builtin_nontemporal_load(&xa[lane]);
        fv4 a1 = __builtin_nontemporal_load(&xa[lane + 64]);
        fv4 a2 = __builtin_nontemporal_load(&xa[lane + 128]);
        fv4 a3 = tail ? __builtin_nontemporal_load(&xa[lane + 192]) : z4;
        fv4 b0 = __builtin_nontemporal_load(&xb[lane]);
        fv4 b1 = __builtin_nontemporal_load(&xb[lane + 64]);
        fv4 b2 = __builtin_nontemporal_load(&xb[lane + 128]);
        fv4 b3 = tail ? __builtin_nontemporal_load(&xb[lane + 192]) : z4;

        float sA0, sA1, sA2, sB0, sB1, sB2;
        {
            fv4 w;
            // chunk 0 (W read once, used for both rows)
            w = w0p[lane];       sA0  = DOT4(a0, w);  sB0  = DOT4(b0, w);
            w = w1p[lane];       sA1  = DOT4(a0, w);  sB1  = DOT4(b0, w);
            w = w2p[lane];       sA2  = DOT4(a0, w);  sB2  = DOT4(b0, w);
            // chunk 1
            w = w0p[lane + 64];  sA0 += DOT4(a1, w);  sB0 += DOT4(b1, w);
            w = w1p[lane + 64];  sA1 += DOT4(a1, w);  sB1 += DOT4(b1, w);
            w = w2p[lane + 64];  sA2 += DOT4(a1, w);  sB2 += DOT4(b1, w);
            // chunk 2
            w = w0p[lane + 128]; sA0 += DOT4(a2, w);  sB0 += DOT4(b2, w);
            w = w1p[lane + 128]; sA1 += DOT4(a2, w);  sB1 += DOT4(b2, w);
            w = w2p[lane + 128]; sA2 += DOT4(a2, w);  sB2 += DOT4(b2, w);
            // chunk 3 (tail; x zeroed for lanes >= 58, W index clamped)
            w = w0p[f3];         sA0 += DOT4(a3, w);  sB0 += DOT4(b3, w);
            w = w1p[f3];         sA1 += DOT4(a3, w);  sB1 += DOT4(b3, w);
            w = w2p[f3];         sA2 += DOT4(a3, w);  sB2 += DOT4(b3, w);
        }

        // Full 64-lane butterfly reduction: 6 independent chains (ILP)
        #pragma unroll
        for (int m = 32; m >= 1; m >>= 1) {
            sA0 += __shfl_xor(sA0, m);
            sA1 += __shfl_xor(sA1, m);
            sA2 += __shfl_xor(sA2, m);
            sB0 += __shfl_xor(sB0, m);
            sB1 += __shfl_xor(sB1, m);
            sB2 += __shfl_xor(sB2, m);
        }
        if (lane == 0) {
            float* yr = y + (size_t)rowA * EDIM;   // rows A,B contiguous: 24 B
            yr[0] = sA0;
            yr[1] = sA1;
            yr[2] = sA2;
            yr[3] = sB0;
            yr[4] = sB1;
            yr[5] = sB2;
        }
    }
}

// ---------------- Stage 1.5: transpose W_fc2 [OUT, 768] -> Wt [768, OUT] ----
__global__ __launch_bounds__(256) void transpose_wfc2(const float* __restrict__ W,
                                                      float* __restrict__ Wt) {
    int idx = blockIdx.x * 256 + threadIdx.x;   // index into Wt (coalesced write)
    if (idx < FC_IN * OUTN) {
        int j = idx >> 7;          // 0..767
        int o = idx & (OUTN - 1);  // 0..127
        Wt[idx] = W[o * FC_IN + j];
    }
}

// ---------------- Stage 2: out[b,o] = sum_j y[b,j] * Wt[j,o] + bias[o] ------
// Round-3 proven version: 512 blocks x 256 threads (128 o x 2 j-halves).
// Stage 2 is L2-latency-bound, not Wt-traffic-bound: max blocks = max TLP.
__global__ __launch_bounds__(256) void stage2_fc(const float* __restrict__ y,
                                                 const float* __restrict__ Wt,
                                                 const float* __restrict__ bias,
                                                 float* __restrict__ out) {
    __shared__ float ys[FC_IN];
    __shared__ float part[OUTN];
    const int b = blockIdx.x;
    for (int i = threadIdx.x; i < FC_IN; i += 256) ys[i] = y[(size_t)b * FC_IN + i];
    __syncthreads();

    const int o = threadIdx.x & (OUTN - 1);
    const int h = threadIdx.x >> 7;               // 0 or 1
    const int j0 = h * (FC_IN / 2);
    float acc = 0.f;
    #pragma unroll 8
    for (int j = j0; j < j0 + FC_IN / 2; ++j) {
        acc += ys[j] * Wt[j * OUTN + o];   // ys[j] broadcast; Wt coalesced across lanes
    }
    if (h) part[o] = acc;
    __syncthreads();
    if (!h) out[(size_t)b * OUTN + o] = acc + part[o] + bias[o];
}

extern "C" void kernel_launch(void* const* d_in, const int* in_sizes, int n_in,
                              void* d_out, int out_size, void* d_ws, size_t ws_size,
                              hipStream_t stream) {
    const float* x     = (const float*)d_in[0];   // [512, 256, 1000]
    const float* W_emb = (const float*)d_in[1];   // [3, 1000]
    const float* W_fc2 = (const float*)d_in[2];   // [128, 768]
    const float* b_fc2 = (const float*)d_in[3];   // [128]
    float* out = (float*)d_out;                   // [512, 128]

    // Workspace layout: y [131072*3] floats, then Wt [768*128] floats
    float* y  = (float*)d_ws;
    float* Wt = y + (size_t)NROWS * EDIM;

    // Transpose fc2 weight first (independent of stage 1)
    transpose_wfc2<<<(FC_IN * OUTN + 255) / 256, 256, 0, stream>>>(W_fc2, Wt);

    // Stage 1: 2048 blocks x 256 threads; each wave does 8 strided row-pairs
    stage1_emb<<<2048, 256, 0, stream>>>(x, W_emb, y);

    // Stage 2: one block per batch row, 256 threads (o x j-half)
    stage2_fc<<<BATCH, 256, 0, stream>>>(y, Wt, b_fc2, out);
}